// Round 8
// baseline (104.367 us; speedup 1.0000x reference)
//
#include <hip/hip_runtime.h>

// HMM posterior: out[b,t,s] = log_softmax_s(alphahat[t]+betahat[t]) — batch-independent
// (per-(b,t) emission scalars cancel in the state-axis softmax; observations unused).
// Linear space: p_t = p0 E^t, q_t = E^(1023-t) 1, E = exp(logA)/max. Global scale of
// p,q cancels in the final log-softmax -> NO per-step rescale in the per-t chains.
//
// Round-8: chain length is proven off the critical path (R4==R7 exactly); the
// remaining cost is the 64-MB store stream (~2-3 TB/s effective vs 6 TB/s fill).
// Mechanism: 256-B chunks at 64-KB stride, with ADJACENT t-chunks on DIFFERENT
// XCDs (round-robin dispatch) -> adjacent lines sit in different L2s -> HBM sees
// isolated 256-B bursts (row-activate bound). Fix, fused (no extra dispatch):
//   * 4 consecutive t per block -> 1-KB contiguous chunk per batch b (4x burst),
//     256 blocks x 256 thr = exactly 1 block/CU.
//   * XCD-contiguous t mapping: tq = (bid%8)*32 + bid/8 -> XCD x owns the
//     contiguous t-range [x*128, x*128+128) -> same-L2 write-back coalescing.
//
// K1 hmm_powers_b4 (verified R5/R7): 15 blocks; block b=(j,d) computes E^(d*4^j)
//    via all-LDS split-bf16 MFMA squarings/mults; single global write at the end.
// K2 hmm_fused4t: 256 blocks x 256 thr; 4 waves = {p(t0,t1), p(t2,t3), q(t0,t1),
//    q(t2,t3)} base-4 chains (coalesced column loads, no per-step reductions);
//    4 log-softmax rows (one per wave); then per-b 1-KB broadcast writes.

#define TT 1024
#define NK 15   // table entries: idx = 3*j + (d-1), j=0..4, d=1..3
#define PS 72   // bf16 plane stride in ushorts (144 B rows: 16B-aligned, 2-way banks = free)

typedef short  bf16x8 __attribute__((ext_vector_type(8)));
typedef float  f32x4  __attribute__((ext_vector_type(4)));

__device__ __forceinline__ unsigned short f2bf(float x) {
    unsigned u = __float_as_uint(x);
    unsigned r = u + 0x7fffu + ((u >> 16) & 1u);   // RNE; inputs finite
    return (unsigned short)(r >> 16);
}
__device__ __forceinline__ float bf2f(unsigned short h) {
    return __uint_as_float(((unsigned)h) << 16);
}

__global__ __launch_bounds__(256) void hmm_powers_b4(const float* __restrict__ logA,
                                                     float* __restrict__ M,
                                                     float* __restrict__ Mt) {
    __shared__ unsigned short Ah[64 * PS], Al[64 * PS];   // X row-major hi/lo
    __shared__ unsigned short Th[64 * PS], Tl[64 * PS];   // X transposed hi/lo
    __shared__ unsigned short Fh[64 * PS], Fl[64 * PS];   // saved F^T hi/lo (B-operand)
    __shared__ float red4[4];
    const int b    = blockIdx.x;        // 0..14
    const int j    = b / 3;
    const int d    = b % 3 + 1;
    const int tid  = threadIdx.x;
    const int wid  = tid >> 6;
    const int lane = tid & 63;

    // ---- Phase 0 (identical in all blocks): E = exp(logA)/max.
    {
        const int row = tid >> 2;
        const int c0  = (tid & 3) * 16;
        float v[16];
        float lmax = 0.f;
        #pragma unroll
        for (int jj = 0; jj < 4; ++jj) {
            float4 x = ((const float4*)logA)[row * 16 + (tid & 3) * 4 + jj];
            float e0 = __expf(x.x), e1 = __expf(x.y), e2 = __expf(x.z), e3 = __expf(x.w);
            v[4 * jj + 0] = e0; v[4 * jj + 1] = e1; v[4 * jj + 2] = e2; v[4 * jj + 3] = e3;
            lmax = fmaxf(lmax, fmaxf(fmaxf(e0, e1), fmaxf(e2, e3)));
        }
        #pragma unroll
        for (int off = 32; off > 0; off >>= 1)
            lmax = fmaxf(lmax, __shfl_xor(lmax, off, 64));
        if (lane == 0) red4[wid] = lmax;
        __syncthreads();
        const float sc = 1.f / fmaxf(fmaxf(red4[0], red4[1]), fmaxf(red4[2], red4[3]));

        if (b == 0) {                   // j=0,d=1: table[0] = E itself, done.
            #pragma unroll
            for (int jj = 0; jj < 16; ++jj) {
                float val = v[jj] * sc;
                int cc = c0 + jj;
                M [row * 64 + cc] = val;
                Mt[cc * 64 + row] = val;
            }
            return;
        }
        #pragma unroll
        for (int jj = 0; jj < 16; ++jj) {
            float val = v[jj] * sc;
            unsigned short hi = f2bf(val);
            unsigned short lo = f2bf(val - bf2f(hi));
            int cc = c0 + jj;
            Ah[row * PS + cc] = hi;  Al[row * PS + cc] = lo;
            Th[cc * PS + row] = hi;  Tl[cc * PS + row] = lo;
        }
    }
    __syncthreads();                    // planes = E, valid for first op

    const int quad = lane >> 4;
    const int l15  = lane & 15;
    const int nsq  = 2 * j;             // squarings to reach F = E^(4^j)
    const int nops = nsq + (d - 1);     // then (d-1) multiplies by F

    for (int op = 0; op < nops; ++op) {
        // Save F^T planes once X == E^(4^j) (threads are synced, planes valid here).
        if (op == nsq && d >= 2) {
            const unsigned* sh = (const unsigned*)Th;  unsigned* dh = (unsigned*)Fh;
            const unsigned* sl = (const unsigned*)Tl;  unsigned* dl = (unsigned*)Fl;
            #pragma unroll
            for (int i = 0; i < 9; ++i) {              // 64*PS/2 = 2304 = 256*9 uints
                dh[tid + 256 * i] = sh[tid + 256 * i];
                dl[tid + 256 * i] = sl[tid + 256 * i];
            }
            __syncthreads();
        }
        const unsigned short* Bh = (op < nsq) ? Th : Fh;
        const unsigned short* Bl = (op < nsq) ? Tl : Fl;

        f32x4 acc[4];
        #pragma unroll
        for (int c = 0; c < 4; ++c) acc[c] = (f32x4){0.f, 0.f, 0.f, 0.f};
        #pragma unroll
        for (int kk = 0; kk < 2; ++kk) {
            const int ao = (16 * wid + l15) * PS + 32 * kk + quad * 8;
            bf16x8 ah = *(const bf16x8*)&Ah[ao];
            bf16x8 al = *(const bf16x8*)&Al[ao];
            #pragma unroll
            for (int c = 0; c < 4; ++c) {
                const int bo = (16 * c + l15) * PS + 32 * kk + quad * 8;
                bf16x8 bh = *(const bf16x8*)&Bh[bo];
                bf16x8 bl = *(const bf16x8*)&Bl[bo];
                acc[c] = __builtin_amdgcn_mfma_f32_16x16x32_bf16(ah, bh, acc[c], 0, 0, 0);
                acc[c] = __builtin_amdgcn_mfma_f32_16x16x32_bf16(ah, bl, acc[c], 0, 0, 0);
                acc[c] = __builtin_amdgcn_mfma_f32_16x16x32_bf16(al, bh, acc[c], 0, 0, 0);
            }
        }
        float m = 0.f;
        #pragma unroll
        for (int c = 0; c < 4; ++c)
            #pragma unroll
            for (int r = 0; r < 4; ++r) m = fmaxf(m, acc[c][r]);
        #pragma unroll
        for (int off = 32; off > 0; off >>= 1)
            m = fmaxf(m, __shfl_xor(m, off, 64));
        if (lane == 0) red4[wid] = m;
        __syncthreads();                // all plane/F reads this op done; red4 ready
        const float sc = 1.f / fmaxf(fmaxf(red4[0], red4[1]), fmaxf(red4[2], red4[3]));

        if (op < nops - 1) {            // rewrite planes (LDS only — no drain)
            #pragma unroll
            for (int c = 0; c < 4; ++c) {
                #pragma unroll
                for (int r = 0; r < 4; ++r) {
                    float val = acc[c][r] * sc;
                    const int rr = 16 * wid + quad * 4 + r;   // C/D: row = quad*4+reg (m89)
                    const int cc = 16 * c   + l15;            //      col = lane&15
                    unsigned short hi = f2bf(val);
                    unsigned short lo = f2bf(val - bf2f(hi));
                    Ah[rr * PS + cc] = hi;  Al[rr * PS + cc] = lo;
                    Th[cc * PS + rr] = hi;  Tl[cc * PS + rr] = lo;
                }
            }
            __syncthreads();            // plane writes visible for next op
        } else {                        // final: single global write of table entry b
            float* Mk  = M  + (b << 12);
            float* Mtk = Mt + (b << 12);
            #pragma unroll
            for (int c = 0; c < 4; ++c) {
                #pragma unroll
                for (int r = 0; r < 4; ++r) {
                    float val = acc[c][r] * sc;
                    const int rr = 16 * wid + quad * 4 + r;
                    const int cc = 16 * c   + l15;
                    Mk [rr * 64 + cc] = val;
                    Mtk[cc * 64 + rr] = val;
                }
            }
        }
    }
}

// Wave-coalesced 64x64 matvec step: v <- v @ Mk (columns of Mk = 256-B coalesced).
__device__ __forceinline__ void matvec64(float* __restrict__ v,
                                         const float* __restrict__ Mk, int lane) {
    float a0 = 0.f, a1 = 0.f, a2 = 0.f, a3 = 0.f;
    #pragma unroll
    for (int i = 0; i < 16; ++i) {
        a0 = fmaf(v[i],      Mk[( i       << 6) + lane], a0);
        a1 = fmaf(v[i + 16], Mk[((i + 16) << 6) + lane], a1);
        a2 = fmaf(v[i + 32], Mk[((i + 32) << 6) + lane], a2);
        a3 = fmaf(v[i + 48], Mk[((i + 48) << 6) + lane], a3);
    }
    v[lane] = (a0 + a1) + (a2 + a3);    // no rescale: scale cancels in softmax
}

// 256 blocks x 256 threads: block handles 4 CONSECUTIVE t (t0..t0+3), mapped so
// each XCD owns a contiguous 128-row t-span. Waves: 0 -> p(t0,t1), 1 -> p(t2,t3),
// 2 -> q(t0,t1), 3 -> q(t2,t3). Base-4 chains, coalesced column loads. Then 4
// log-softmax rows (one per wave) and per-b 1-KB broadcast chunks (4 rows x 256 B).
__global__ __launch_bounds__(256) void hmm_fused4t(const float* __restrict__ M,
                                                   const float* __restrict__ Mt,
                                                   const float* __restrict__ logInit,
                                                   float* __restrict__ out) {
    // XCD-contiguous t mapping: blocks dispatch round-robin to XCDs (bid%8);
    // give XCD x the quads [x*32, x*32+32) -> t in [x*128, x*128+128).
    const int tq = ((blockIdx.x & 7) << 5) + (blockIdx.x >> 3);   // bijective, 256=8*32
    const int t0 = tq << 2;
    __shared__ float sp[4][64];
    __shared__ float sq[4][64];
    __shared__ float sgr[4][64];
    const int tid  = threadIdx.x;
    const int wid  = tid >> 6;
    const int lane = tid & 63;

    {
        const int isQ  = wid >> 1;
        const int cA   = (wid & 1) * 2;
        const int cB   = cA + 1;
        float* vA = isQ ? sq[cA] : sp[cA];
        float* vB = isQ ? sq[cB] : sp[cB];
        const float* tbl = isQ ? Mt : M;
        const int eA = isQ ? (TT - 1) - (t0 + cA) : (t0 + cA);
        const int eB = isQ ? (TT - 1) - (t0 + cB) : (t0 + cB);
        const float init = isQ ? 1.f : __expf(logInit[lane]);
        vA[lane] = init;
        vB[lane] = init;
        #pragma unroll
        for (int j = 0; j < 5; ++j) {
            const int dA = (eA >> (2 * j)) & 3;
            const int dB = (eB >> (2 * j)) & 3;
            if (dA) matvec64(vA, tbl + ((3 * j + dA - 1) << 12), lane);
            if (dB) matvec64(vB, tbl + ((3 * j + dB - 1) << 12), lane);
        }
    }
    __syncthreads();                    // all 8 chain rows final

    {   // wave wid computes log-softmax of row wid (t = t0 + wid)
        float gv = __logf(sp[wid][lane]) + __logf(sq[wid][lane]);
        float mx = gv;
        #pragma unroll
        for (int off = 32; off > 0; off >>= 1)
            mx = fmaxf(mx, __shfl_xor(mx, off, 64));
        float ex = __expf(gv - mx);
        float sm = ex;
        #pragma unroll
        for (int off = 32; off > 0; off >>= 1)
            sm += __shfl_xor(sm, off, 64);
        sgr[wid][lane] = gv - mx - __logf(sm);
    }
    __syncthreads();

    // Broadcast: for each batch b, write the 1-KB chunk out[b][t0..t0+3][0..63].
    // 64-thread group g handles b = it*4 + g; its 64 lanes cover 4 rows x 16 float4
    // = 1 KB contiguous (lane c: row = c>>4, s4 = c&15).
    const int g  = tid >> 6;            // 0..3
    const int c  = tid & 63;
    float4 val = ((const float4*)sgr)[c];              // sgr[4][64] = 64 float4
    float4* o4 = (float4*)out;
    const size_t base = (size_t)(t0 + (c >> 4)) * 16 + (c & 15);   // f4 units
    #pragma unroll
    for (int it = 0; it < 64; ++it) {
        const int b = (it << 2) + g;
        o4[(size_t)b * 16384 + base] = val;
    }
}

extern "C" void kernel_launch(void* const* d_in, const int* in_sizes, int n_in,
                              void* d_out, int out_size, void* d_ws, size_t ws_size,
                              hipStream_t stream) {
    // inputs: [0] observations (unused), [1] log_transition (64x64 f32),
    //         [2] log_initial (64 f32), [3] log_emission (unused)
    const float* logA    = (const float*)d_in[1];
    const float* logInit = (const float*)d_in[2];
    float* M  = (float*)d_ws;              // 15 * 4096 floats
    float* Mt = M + NK * 4096;             // 15 * 4096 floats (480 KB of ws)
    hmm_powers_b4<<<NK, 256, 0, stream>>>(logA, M, Mt);
    hmm_fused4t<<<256, 256, 0, stream>>>(M, Mt, logInit, (float*)d_out);
}

// Round 10
// 102.443 us; speedup vs baseline: 1.0188x; 1.0188x over previous
//
#include <hip/hip_runtime.h>

// HMM posterior: out[b,t,s] = log_softmax_s(alphahat[t]+betahat[t]) — batch-independent
// (per-(b,t) emission scalars cancel in the state-axis softmax; observations unused).
// Linear space: p_t = p0 E^t, q_t = E^(1023-t) 1, E = exp(logA)/max. Global scale of
// p,q cancels in the final log-softmax -> NO per-step rescale in the per-t chains.
//
// Round-10 = round-9 retry (compile fix only): __builtin_nontemporal_store requires
// a native ext-vector type, not HIP's float4 class -> store through f32x4.
// Theory unchanged: all spatial write restructures (256-B scatter / contiguous
// streams / 1-KB XCD-local bursts) measured identical -> limiter is temporal:
// 64 MB streaming through the 16x-smaller write-back L2 scrambles HBM write-back
// order. nt stores bypass L2 write-allocate and stream in issue order like the
// 6-TB/s fills.
//
// K1 hmm_powers_b4: 15 blocks; block b=(j,d) computes E^(d*4^j) via all-LDS
//    split-bf16 MFMA squarings/mults; single global write at the end (~4 us).
// K2 hmm_fused_b4c: 1024 blocks x 128 thr; base-4 chains (coalesced column loads,
//    no per-step reductions), log-softmax row, nt broadcast scatter-write.

#define TT 1024
#define NK 15   // table entries: idx = 3*j + (d-1), j=0..4, d=1..3
#define PS 72   // bf16 plane stride in ushorts (144 B rows: 16B-aligned, 2-way banks = free)

typedef short  bf16x8 __attribute__((ext_vector_type(8)));
typedef float  f32x4  __attribute__((ext_vector_type(4)));

__device__ __forceinline__ unsigned short f2bf(float x) {
    unsigned u = __float_as_uint(x);
    unsigned r = u + 0x7fffu + ((u >> 16) & 1u);   // RNE; inputs finite
    return (unsigned short)(r >> 16);
}
__device__ __forceinline__ float bf2f(unsigned short h) {
    return __uint_as_float(((unsigned)h) << 16);
}

__global__ __launch_bounds__(256) void hmm_powers_b4(const float* __restrict__ logA,
                                                     float* __restrict__ M,
                                                     float* __restrict__ Mt) {
    __shared__ unsigned short Ah[64 * PS], Al[64 * PS];   // X row-major hi/lo
    __shared__ unsigned short Th[64 * PS], Tl[64 * PS];   // X transposed hi/lo
    __shared__ unsigned short Fh[64 * PS], Fl[64 * PS];   // saved F^T hi/lo (B-operand)
    __shared__ float red4[4];
    const int b    = blockIdx.x;        // 0..14
    const int j    = b / 3;
    const int d    = b % 3 + 1;
    const int tid  = threadIdx.x;
    const int wid  = tid >> 6;
    const int lane = tid & 63;

    // ---- Phase 0 (identical in all blocks): E = exp(logA)/max.
    {
        const int row = tid >> 2;
        const int c0  = (tid & 3) * 16;
        float v[16];
        float lmax = 0.f;
        #pragma unroll
        for (int jj = 0; jj < 4; ++jj) {
            float4 x = ((const float4*)logA)[row * 16 + (tid & 3) * 4 + jj];
            float e0 = __expf(x.x), e1 = __expf(x.y), e2 = __expf(x.z), e3 = __expf(x.w);
            v[4 * jj + 0] = e0; v[4 * jj + 1] = e1; v[4 * jj + 2] = e2; v[4 * jj + 3] = e3;
            lmax = fmaxf(lmax, fmaxf(fmaxf(e0, e1), fmaxf(e2, e3)));
        }
        #pragma unroll
        for (int off = 32; off > 0; off >>= 1)
            lmax = fmaxf(lmax, __shfl_xor(lmax, off, 64));
        if (lane == 0) red4[wid] = lmax;
        __syncthreads();
        const float sc = 1.f / fmaxf(fmaxf(red4[0], red4[1]), fmaxf(red4[2], red4[3]));

        if (b == 0) {                   // j=0,d=1: table[0] = E itself, done.
            #pragma unroll
            for (int jj = 0; jj < 16; ++jj) {
                float val = v[jj] * sc;
                int cc = c0 + jj;
                M [row * 64 + cc] = val;
                Mt[cc * 64 + row] = val;
            }
            return;
        }
        #pragma unroll
        for (int jj = 0; jj < 16; ++jj) {
            float val = v[jj] * sc;
            unsigned short hi = f2bf(val);
            unsigned short lo = f2bf(val - bf2f(hi));
            int cc = c0 + jj;
            Ah[row * PS + cc] = hi;  Al[row * PS + cc] = lo;
            Th[cc * PS + row] = hi;  Tl[cc * PS + row] = lo;
        }
    }
    __syncthreads();                    // planes = E, valid for first op

    const int quad = lane >> 4;
    const int l15  = lane & 15;
    const int nsq  = 2 * j;             // squarings to reach F = E^(4^j)
    const int nops = nsq + (d - 1);     // then (d-1) multiplies by F

    for (int op = 0; op < nops; ++op) {
        // Save F^T planes once X == E^(4^j) (threads are synced, planes valid here).
        if (op == nsq && d >= 2) {
            const unsigned* sh = (const unsigned*)Th;  unsigned* dh = (unsigned*)Fh;
            const unsigned* sl = (const unsigned*)Tl;  unsigned* dl = (unsigned*)Fl;
            #pragma unroll
            for (int i = 0; i < 9; ++i) {              // 64*PS/2 = 2304 = 256*9 uints
                dh[tid + 256 * i] = sh[tid + 256 * i];
                dl[tid + 256 * i] = sl[tid + 256 * i];
            }
            __syncthreads();
        }
        const unsigned short* Bh = (op < nsq) ? Th : Fh;
        const unsigned short* Bl = (op < nsq) ? Tl : Fl;

        f32x4 acc[4];
        #pragma unroll
        for (int c = 0; c < 4; ++c) acc[c] = (f32x4){0.f, 0.f, 0.f, 0.f};
        #pragma unroll
        for (int kk = 0; kk < 2; ++kk) {
            const int ao = (16 * wid + l15) * PS + 32 * kk + quad * 8;
            bf16x8 ah = *(const bf16x8*)&Ah[ao];
            bf16x8 al = *(const bf16x8*)&Al[ao];
            #pragma unroll
            for (int c = 0; c < 4; ++c) {
                const int bo = (16 * c + l15) * PS + 32 * kk + quad * 8;
                bf16x8 bh = *(const bf16x8*)&Bh[bo];
                bf16x8 bl = *(const bf16x8*)&Bl[bo];
                acc[c] = __builtin_amdgcn_mfma_f32_16x16x32_bf16(ah, bh, acc[c], 0, 0, 0);
                acc[c] = __builtin_amdgcn_mfma_f32_16x16x32_bf16(ah, bl, acc[c], 0, 0, 0);
                acc[c] = __builtin_amdgcn_mfma_f32_16x16x32_bf16(al, bh, acc[c], 0, 0, 0);
            }
        }
        float m = 0.f;
        #pragma unroll
        for (int c = 0; c < 4; ++c)
            #pragma unroll
            for (int r = 0; r < 4; ++r) m = fmaxf(m, acc[c][r]);
        #pragma unroll
        for (int off = 32; off > 0; off >>= 1)
            m = fmaxf(m, __shfl_xor(m, off, 64));
        if (lane == 0) red4[wid] = m;
        __syncthreads();                // all plane/F reads this op done; red4 ready
        const float sc = 1.f / fmaxf(fmaxf(red4[0], red4[1]), fmaxf(red4[2], red4[3]));

        if (op < nops - 1) {            // rewrite planes (LDS only — no drain)
            #pragma unroll
            for (int c = 0; c < 4; ++c) {
                #pragma unroll
                for (int r = 0; r < 4; ++r) {
                    float val = acc[c][r] * sc;
                    const int rr = 16 * wid + quad * 4 + r;   // C/D: row = quad*4+reg (m89)
                    const int cc = 16 * c   + l15;            //      col = lane&15
                    unsigned short hi = f2bf(val);
                    unsigned short lo = f2bf(val - bf2f(hi));
                    Ah[rr * PS + cc] = hi;  Al[rr * PS + cc] = lo;
                    Th[cc * PS + rr] = hi;  Tl[cc * PS + rr] = lo;
                }
            }
            __syncthreads();            // plane writes visible for next op
        } else {                        // final: single global write of table entry b
            float* Mk  = M  + (b << 12);
            float* Mtk = Mt + (b << 12);
            #pragma unroll
            for (int c = 0; c < 4; ++c) {
                #pragma unroll
                for (int r = 0; r < 4; ++r) {
                    float val = acc[c][r] * sc;
                    const int rr = 16 * wid + quad * 4 + r;
                    const int cc = 16 * c   + l15;
                    Mk [rr * 64 + cc] = val;
                    Mtk[cc * 64 + rr] = val;
                }
            }
        }
    }
}

// 1024 blocks x 128 threads: wave 0 -> p-chain, wave 1 -> q-chain. Base-4 digits
// (<=5 steps/chain), wave-coalesced scalar column loads (256 B/instr), no per-step
// reductions. Then log-softmax row + NON-TEMPORAL broadcast scatter-write.
__global__ __launch_bounds__(128) void hmm_fused_b4c(const float* __restrict__ M,
                                                     const float* __restrict__ Mt,
                                                     const float* __restrict__ logInit,
                                                     float* __restrict__ out) {
    const int t = blockIdx.x;
    __shared__ float sp[64];
    __shared__ float sq[64];
    __shared__ float sgr[64];
    const int lane = threadIdx.x & 63;
    const int w    = threadIdx.x >> 6;

    if (w == 0) {
        sp[lane] = __expf(logInit[lane]);
        const int e = t;
        #pragma unroll
        for (int j = 0; j < 5; ++j) {
            const int dj = (e >> (2 * j)) & 3;
            if (dj) {
                const float* Mk = M + ((3 * j + dj - 1) << 12);
                float a0 = 0.f, a1 = 0.f, a2 = 0.f, a3 = 0.f;
                #pragma unroll
                for (int i = 0; i < 16; ++i) {
                    a0 = fmaf(sp[i],      Mk[( i       << 6) + lane], a0);
                    a1 = fmaf(sp[i + 16], Mk[((i + 16) << 6) + lane], a1);
                    a2 = fmaf(sp[i + 32], Mk[((i + 32) << 6) + lane], a2);
                    a3 = fmaf(sp[i + 48], Mk[((i + 48) << 6) + lane], a3);
                }
                sp[lane] = (a0 + a1) + (a2 + a3);   // no rescale: scale cancels in softmax
            }
        }
    } else {
        sq[lane] = 1.f;
        const int e = (TT - 1) - t;
        #pragma unroll
        for (int j = 0; j < 5; ++j) {
            const int dj = (e >> (2 * j)) & 3;
            if (dj) {
                const float* Mk = Mt + ((3 * j + dj - 1) << 12);
                float a0 = 0.f, a1 = 0.f, a2 = 0.f, a3 = 0.f;
                #pragma unroll
                for (int i = 0; i < 16; ++i) {
                    a0 = fmaf(sq[i],      Mk[( i       << 6) + lane], a0);
                    a1 = fmaf(sq[i + 16], Mk[((i + 16) << 6) + lane], a1);
                    a2 = fmaf(sq[i + 32], Mk[((i + 32) << 6) + lane], a2);
                    a3 = fmaf(sq[i + 48], Mk[((i + 48) << 6) + lane], a3);
                }
                sq[lane] = (a0 + a1) + (a2 + a3);
            }
        }
    }
    __syncthreads();

    if (w == 0) {
        float gv = __logf(sp[lane]) + __logf(sq[lane]);
        float mx = gv;
        #pragma unroll
        for (int off = 32; off > 0; off >>= 1)
            mx = fmaxf(mx, __shfl_xor(mx, off, 64));
        float ex = __expf(gv - mx);
        float sm = ex;
        #pragma unroll
        for (int off = 32; off > 0; off >>= 1)
            sm += __shfl_xor(sm, off, 64);
        sgr[lane] = gv - mx - __logf(sm);
    }
    __syncthreads();

    // Broadcast row t to all 256 batches: out[b][t][0..63], 256-B chunks, 16-B
    // NON-TEMPORAL stores (nt: bypass L2 write-allocate, stream in issue order).
    // f32x4 (ext_vector_type) — __builtin_nontemporal_store rejects HIP float4.
    const int s4 = threadIdx.x & 15;
    const int b0 = threadIdx.x >> 4;                 // 0..7
    f32x4 val = *((const f32x4*)sgr + s4);
    f32x4* o4 = (f32x4*)out;
    const size_t trow = (size_t)t * 16 + s4;
    #pragma unroll
    for (int it = 0; it < 32; ++it) {
        int b = (it << 3) + b0;
        __builtin_nontemporal_store(val, o4 + (size_t)b * 16384 + trow);
    }
}

extern "C" void kernel_launch(void* const* d_in, const int* in_sizes, int n_in,
                              void* d_out, int out_size, void* d_ws, size_t ws_size,
                              hipStream_t stream) {
    // inputs: [0] observations (unused), [1] log_transition (64x64 f32),
    //         [2] log_initial (64 f32), [3] log_emission (unused)
    const float* logA    = (const float*)d_in[1];
    const float* logInit = (const float*)d_in[2];
    float* M  = (float*)d_ws;              // 15 * 4096 floats
    float* Mt = M + NK * 4096;             // 15 * 4096 floats (480 KB of ws)
    hmm_powers_b4<<<NK, 256, 0, stream>>>(logA, M, Mt);
    hmm_fused_b4c<<<TT, 128, 0, stream>>>(M, Mt, logInit, (float*)d_out);
}